// Round 5
// baseline (486.663 us; speedup 1.0000x reference)
//
#include <hip/hip_runtime.h>

#define NBATCH 4
#define NPTS   16384
#define BN     (NBATCH * NPTS)   // 65536 points

typedef __attribute__((ext_vector_type(8))) _Float16 half8;
typedef __attribute__((ext_vector_type(4))) float f32x4;

#define INV4096 2.44140625e-4f

// ---------- split-fp16 (hi + lo*2^-12 ~ fp32 accuracy) ----------
__device__ __forceinline__ void splith(float x, _Float16& h, _Float16& l) {
  float ax = __builtin_fabsf(x);
  if (ax < 6.1035e-5f) {
    unsigned short sb = (unsigned short)((__float_as_uint(x) >> 16) & 0x8000u);
    h = __builtin_bit_cast(_Float16, sb);          // +/-0 preserves sign for relu
    l = (_Float16)(x * 4096.f);
  } else {
    _Float16 hh = (_Float16)x;
    h = hh;
    l = (_Float16)((x - (float)hh) * 4096.f);      // x-hh exact (Sterbenz)
  }
}
__device__ __forceinline__ void splith8(const float v[8], half8& hi, half8& lo) {
  #pragma unroll
  for (int j = 0; j < 8; ++j) { _Float16 h, l; splith(v[j], h, l); hi[j] = h; lo[j] = l; }
}

// zero halves of v where the corresponding half of sgn has its sign bit set
__device__ __forceinline__ half8 relu8(half8 sgn, half8 v) {
  uint4 s = __builtin_bit_cast(uint4, sgn);
  uint4 x = __builtin_bit_cast(uint4, v);
  unsigned* sp = (unsigned*)&s;
  unsigned* xp = (unsigned*)&x;
  uint4 out;
  unsigned* op = (unsigned*)&out;
  #pragma unroll
  for (int w = 0; w < 4; ++w) {
    unsigned m = sp[w] & 0x80008000u;
    unsigned drop = (m - (m >> 15)) | m;   // 0xFFFF per negative half
    op[w] = xp[w] & ~drop;
  }
  return __builtin_bit_cast(half8, out);
}

// ---------- utility kernels ----------
__global__ void k_zero4(float4* __restrict__ p, int n4) {
  int g = blockIdx.x * 256 + threadIdx.x;
  if (g < n4) p[g] = make_float4(0.f, 0.f, 0.f, 0.f);
}

__global__ void k_idx(const float* __restrict__ pts, int* __restrict__ idx,
                      int* __restrict__ cnti) {
  int g = blockIdx.x * 256 + threadIdx.x;
  if (g >= BN) return;
  int b = g >> 14;
  float px = pts[g * 3 + 0], py = pts[g * 3 + 1];
  int xi = (int)(px * 128.f); xi = xi < 0 ? 0 : (xi > 127 ? 127 : xi);
  int yi = (int)(py * 128.f); yi = yi < 0 ? 0 : (yi > 127 ? 127 : yi);
  int id = xi + (yi << 7);
  idx[g] = id;
  atomicAdd(&cnti[(b << 14) + id], 1);
}

// per-batch exclusive scan of cnti -> global sorted offsets (batch base folded in)
__global__ void k_scan(const int* __restrict__ cnti, int* __restrict__ off,
                       int* __restrict__ cursor) {
  __shared__ int part[256];
  const int b = blockIdx.x, t = threadIdx.x;
  const int base = b << 14;
  int s = 0;
  #pragma unroll 8
  for (int i = 0; i < 64; ++i) s += cnti[base + t * 64 + i];
  part[t] = s;
  __syncthreads();
  for (int o = 1; o < 256; o <<= 1) {       // Hillis-Steele inclusive scan
    int v = (t >= o) ? part[t - o] : 0;
    __syncthreads();
    part[t] += v;
    __syncthreads();
  }
  int run = base + (t == 0 ? 0 : part[t - 1]);   // global position base
  #pragma unroll 8
  for (int i = 0; i < 64; ++i) {
    int g = base + t * 64 + i;
    off[g] = run;
    cursor[g] = run;
    run += cnti[g];
  }
}

__global__ void k_scatter(const int* __restrict__ idx, int* __restrict__ cursor,
                          int* __restrict__ perm, int* __restrict__ sbin) {
  int p = blockIdx.x * 256 + threadIdx.x;
  if (p >= BN) return;
  int b = p >> 14;
  int id = idx[p];
  int pos = atomicAdd(&cursor[(b << 14) + id], 1);
  perm[pos] = p;
  sbin[pos] = id;
}

// ---------- pack weights into frag-ordered split-fp16 planes ----------
__device__ __forceinline__ void pack_slot(const float* __restrict__ src, int K,
                                          _Float16* __restrict__ dhi, int NK,
                                          int slot) {
  int fpt = (K >> 5) << 6;                 // frags per 16-row tile
  int t = slot / fpt, rem = slot - t * fpt;
  int s = rem >> 6, lane = rem & 63;
  int row = (t << 4) + (lane & 15);
  int k0 = (s << 5) + ((lane >> 4) << 3);
  float v[8];
  #pragma unroll
  for (int j = 0; j < 8; ++j) v[j] = src[row * K + k0 + j];
  half8 hi, lo; splith8(v, hi, lo);
  *(half8*)&dhi[(size_t)slot << 3] = hi;
  *(half8*)&dhi[((size_t)slot << 3) + NK] = lo;
}

__global__ void k_pack(const float* __restrict__ fc0w, const float* __restrict__ scw,
                       const float* __restrict__ fc1w, const float* __restrict__ fccw,
                       _Float16* __restrict__ wp) {
  int g = blockIdx.x * 256 + threadIdx.x;     // total 53248 slots
  if (g < 20480) {                            // fc0: 5 layers x 4096 slots
    int l = g >> 12, slot = g & 4095;
    pack_slot(fc0w + (size_t)l * 32768, 256, wp + (size_t)l * 65536, 32768, slot);
  } else if (g < 40960) {                     // sc
    int g2 = g - 20480; int l = g2 >> 12, slot = g2 & 4095;
    pack_slot(scw + (size_t)l * 32768, 256, wp + 327680 + (size_t)l * 65536, 32768, slot);
  } else if (g < 51200) {                     // fc1: 5 x 2048 slots
    int g2 = g - 40960; int l = g2 >> 11, slot = g2 & 2047;
    pack_slot(fc1w + (size_t)l * 16384, 128, wp + 655360 + (size_t)l * 32768, 16384, slot);
  } else {                                    // fc_c: 2048 slots
    int slot = g - 51200;
    pack_slot(fccw, 128, wp + 819200, 16384, slot);
  }
}

// ---------- fused ResnetBlockFC (MFMA, split-fp16), 32 sorted pts/block ----------
// All rows are in bin-sorted order. No atomics anywhere.
template <int SRC>
__launch_bounds__(256, 4)
__global__ void k_rb(const float* __restrict__ pts, const float* __restrict__ binsIn,
                     const int* __restrict__ perm, const int* __restrict__ sbin,
                     const float* __restrict__ posw, const float* __restrict__ posb,
                     const _Float16* __restrict__ w0p, const float* __restrict__ b0,
                     const _Float16* __restrict__ w1p, const float* __restrict__ b1,
                     const _Float16* __restrict__ wsp,
                     float* net) {
  extern __shared__ _Float16 smem[];          // 32 KB
  _Float16* Ahi = smem;                       // 8192 f16
  _Float16* Alo = smem + 8192;
  const int tid = threadIdx.x;
  const int lane = tid & 63, wave = tid >> 6;
  const int p0 = blockIdx.x << 5;             // 32 sorted points
  const int b = p0 >> 14;

  // ---- stage x (hi/lo frag planes, XOR-swizzled) ----
  #pragma unroll
  for (int i = 0; i < 4; ++i) {
    int sidx = tid + (i << 8);                // 1024 slots
    int m = sidx >> 5, kslot = sidx & 31, k0 = kslot << 3;
    float v[8];
    if (SRC == 0) {
      const float* pp = &pts[(size_t)perm[p0 + m] * 3];
      float px = pp[0], py = pp[1], pz = pp[2];
      #pragma unroll
      for (int j = 0; j < 8; ++j) {
        int c = k0 + j;
        v[j] = fmaf(posw[c * 3 + 0], px,
               fmaf(posw[c * 3 + 1], py,
               fmaf(posw[c * 3 + 2], pz, posb[c])));
      }
    } else {
      if (kslot < 16) {
        float4 a = *(const float4*)&net[(size_t)(p0 + m) * 128 + k0];
        float4 c = *(const float4*)&net[(size_t)(p0 + m) * 128 + k0 + 4];
        v[0] = a.x; v[1] = a.y; v[2] = a.z; v[3] = a.w;
        v[4] = c.x; v[5] = c.y; v[6] = c.z; v[7] = c.w;
      } else {
        int rb_ = sbin[p0 + m];
        const float* brow = &binsIn[(size_t)(((b << 14) + rb_) << 7) + (k0 - 128)];
        float4 a = *(const float4*)brow;
        float4 c = *(const float4*)(brow + 4);
        v[0] = a.x; v[1] = a.y; v[2] = a.z; v[3] = a.w;
        v[4] = c.x; v[5] = c.y; v[6] = c.z; v[7] = c.w;
      }
    }
    half8 hi, lo; splith8(v, hi, lo);
    int mt = m >> 4, mm = m & 15, s = kslot >> 2, quad = kslot & 3;
    int ln = mm + (quad << 4), kg = (mt << 3) + s;   // kg in [0,16)
    int u = (kg << 6) + (ln ^ (kg & 7));
    *(half8*)&Ahi[u << 3] = hi;
    *(half8*)&Alo[u << 3] = lo;
  }
  __syncthreads();

  // ---- combined K-loop: h = relu(x)@w0+b0 ; s = x@ws+b1 (main + cross acc) ----
  f32x4 hm[2][2], hc[2][2], so[2][2], sc[2][2];
  {
    int col = lane & 15;
    #pragma unroll
    for (int nt = 0; nt < 2; ++nt) {
      float bv0 = b0[(wave << 5) + (nt << 4) + col];
      float bv1 = b1[(wave << 5) + (nt << 4) + col];
      #pragma unroll
      for (int mt = 0; mt < 2; ++mt) {
        hm[mt][nt] = (f32x4){bv0, bv0, bv0, bv0};
        so[mt][nt] = (f32x4){bv1, bv1, bv1, bv1};
        hc[mt][nt] = (f32x4){0.f, 0.f, 0.f, 0.f};
        sc[mt][nt] = (f32x4){0.f, 0.f, 0.f, 0.f};
      }
    }
  }
  const _Float16* w0lo = w0p + 32768;
  const _Float16* wslo = wsp + 32768;

  half8 c0h[2], c0l[2], csh[2], csl[2];
  #pragma unroll
  for (int nt = 0; nt < 2; ++nt) {            // preload ks = 0
    int t = (wave << 1) + nt;
    size_t fo = (((size_t)(t << 3) << 6) + lane) << 3;
    c0h[nt] = *(const half8*)&w0p[fo];
    c0l[nt] = *(const half8*)&w0lo[fo];
    csh[nt] = *(const half8*)&wsp[fo];
    csl[nt] = *(const half8*)&wslo[fo];
  }
  for (int ks = 0; ks < 8; ++ks) {
    half8 n0h[2], n0l[2], nsh[2], nsl[2];
    int ksn = (ks + 1) & 7;
    #pragma unroll
    for (int nt = 0; nt < 2; ++nt) {
      int t = (wave << 1) + nt;
      size_t fo = (((size_t)((t << 3) + ksn) << 6) + lane) << 3;
      n0h[nt] = *(const half8*)&w0p[fo];
      n0l[nt] = *(const half8*)&w0lo[fo];
      nsh[nt] = *(const half8*)&wsp[fo];
      nsl[nt] = *(const half8*)&wslo[fo];
    }
    #pragma unroll
    for (int mt = 0; mt < 2; ++mt) {
      int kg = (mt << 3) + ks;
      int u = (kg << 6) + (lane ^ (kg & 7));
      half8 ah = *(const half8*)&Ahi[u << 3];
      half8 al = *(const half8*)&Alo[u << 3];
      half8 arh = relu8(ah, ah);
      half8 arl = relu8(ah, al);
      #pragma unroll
      for (int nt = 0; nt < 2; ++nt) {
        hm[mt][nt] = __builtin_amdgcn_mfma_f32_16x16x32_f16(arh, c0h[nt], hm[mt][nt], 0, 0, 0);
        hc[mt][nt] = __builtin_amdgcn_mfma_f32_16x16x32_f16(arl, c0h[nt], hc[mt][nt], 0, 0, 0);
        hc[mt][nt] = __builtin_amdgcn_mfma_f32_16x16x32_f16(arh, c0l[nt], hc[mt][nt], 0, 0, 0);
        so[mt][nt] = __builtin_amdgcn_mfma_f32_16x16x32_f16(ah,  csh[nt], so[mt][nt], 0, 0, 0);
        sc[mt][nt] = __builtin_amdgcn_mfma_f32_16x16x32_f16(al,  csh[nt], sc[mt][nt], 0, 0, 0);
        sc[mt][nt] = __builtin_amdgcn_mfma_f32_16x16x32_f16(ah,  csl[nt], sc[mt][nt], 0, 0, 0);
      }
    }
    #pragma unroll
    for (int nt = 0; nt < 2; ++nt) {
      c0h[nt] = n0h[nt]; c0l[nt] = n0l[nt];
      csh[nt] = nsh[nt]; csl[nt] = nsl[nt];
    }
  }
  __syncthreads();   // x planes dead; overlay h frags

  // ---- write relu(h) into A2 frag planes (K2 = 128) ----
  _Float16* A2hi = smem;                      // 4096 f16
  _Float16* A2lo = smem + 4096;
  {
    int q = lane >> 4, j2 = lane & 7, qh = (lane & 15) >> 3;
    #pragma unroll
    for (int mt = 0; mt < 2; ++mt) {
      int kg2 = (mt << 2) + wave;             // [0,8)
      #pragma unroll
      for (int nt = 0; nt < 2; ++nt) {
        int quad2 = (nt << 1) + qh;
        #pragma unroll
        for (int r = 0; r < 4; ++r) {
          float hv = fmaxf(fmaf(hc[mt][nt][r], INV4096, hm[mt][nt][r]), 0.f);
          _Float16 hb, lb; splith(hv, hb, lb);
          int mm2 = (q << 2) + r;
          int ln2 = mm2 + (quad2 << 4);
          int u2 = (kg2 << 6) + (ln2 ^ (kg2 & 7));
          A2hi[(u2 << 3) + j2] = hb;
          A2lo[(u2 << 3) + j2] = lb;
        }
      }
    }
  }
  __syncthreads();

  // ---- GEMM1: s += relu(h) @ w1 ----
  const _Float16* w1lo = w1p + 16384;
  half8 w1ch[2], w1cl[2];
  #pragma unroll
  for (int nt = 0; nt < 2; ++nt) {
    int t = (wave << 1) + nt;
    size_t fo = (((size_t)(t << 2) << 6) + lane) << 3;
    w1ch[nt] = *(const half8*)&w1p[fo];
    w1cl[nt] = *(const half8*)&w1lo[fo];
  }
  for (int ks = 0; ks < 4; ++ks) {
    half8 nh[2], nl[2];
    int ksn = (ks + 1) & 3;
    #pragma unroll
    for (int nt = 0; nt < 2; ++nt) {
      int t = (wave << 1) + nt;
      size_t fo = (((size_t)((t << 2) + ksn) << 6) + lane) << 3;
      nh[nt] = *(const half8*)&w1p[fo];
      nl[nt] = *(const half8*)&w1lo[fo];
    }
    #pragma unroll
    for (int mt = 0; mt < 2; ++mt) {
      int kg = (mt << 2) + ks;
      int u = (kg << 6) + (lane ^ (kg & 7));
      half8 ah = *(const half8*)&A2hi[u << 3];
      half8 al = *(const half8*)&A2lo[u << 3];
      #pragma unroll
      for (int nt = 0; nt < 2; ++nt) {
        so[mt][nt] = __builtin_amdgcn_mfma_f32_16x16x32_f16(ah, w1ch[nt], so[mt][nt], 0, 0, 0);
        sc[mt][nt] = __builtin_amdgcn_mfma_f32_16x16x32_f16(al, w1ch[nt], sc[mt][nt], 0, 0, 0);
        sc[mt][nt] = __builtin_amdgcn_mfma_f32_16x16x32_f16(ah, w1cl[nt], sc[mt][nt], 0, 0, 0);
      }
    }
    #pragma unroll
    for (int nt = 0; nt < 2; ++nt) { w1ch[nt] = nh[nt]; w1cl[nt] = nl[nt]; }
  }

  // ---- epilogue: plain store (sorted rows) ----
  {
    int col = lane & 15, q = lane >> 4;
    #pragma unroll
    for (int mt = 0; mt < 2; ++mt) {
      #pragma unroll
      for (int r = 0; r < 4; ++r) {
        int m_g = p0 + (mt << 4) + (q << 2) + r;
        #pragma unroll
        for (int nt = 0; nt < 2; ++nt) {
          int n = (wave << 5) + (nt << 4) + col;
          net[(size_t)m_g * 128 + n] = fmaf(sc[mt][nt][r], INV4096, so[mt][nt][r]);
        }
      }
    }
  }
}

// ---------- segment max over contiguous sorted rows (one wave per bin) ----------
__launch_bounds__(256)
__global__ void k_seg(const float* __restrict__ net, const int* __restrict__ off,
                      const int* __restrict__ cnti, float* __restrict__ bins) {
  int g = blockIdx.x * 4 + (threadIdx.x >> 6);   // global bin id (b*16384+bin)
  int lane = threadIdx.x & 63;
  int n = cnti[g];
  if (n == 0) return;                             // empty bins never gathered
  int s = off[g];
  int c2 = lane << 1;
  float2 mx = *(const float2*)&net[(size_t)s * 128 + c2];
  for (int r = 1; r < n; ++r) {
    float2 v = *(const float2*)&net[(size_t)(s + r) * 128 + c2];
    mx.x = fmaxf(mx.x, v.x); mx.y = fmaxf(mx.y, v.y);
  }
  *(float2*)&bins[((size_t)g << 7) + c2] = mx;
}

// ---------- segment mean over contiguous sorted rows (empty bins -> 0) ----------
__launch_bounds__(256)
__global__ void k_segsum(const float* __restrict__ cnet, const int* __restrict__ off,
                         const int* __restrict__ cnti, float* __restrict__ sums) {
  int g = blockIdx.x * 4 + (threadIdx.x >> 6);
  int lane = threadIdx.x & 63;
  int n = cnti[g];
  int c2 = lane << 1;
  float2 acc = make_float2(0.f, 0.f);
  int s = off[g];
  for (int r = 0; r < n; ++r) {
    float2 v = *(const float2*)&cnet[(size_t)(s + r) * 128 + c2];
    acc.x += v.x; acc.y += v.y;
  }
  *(float2*)&sums[((size_t)g << 7) + c2] = acc;
}

// ---------- final linear (MFMA), plain store to sorted rows ----------
__launch_bounds__(256, 4)
__global__ void k_fcc(const float* __restrict__ net,
                      const _Float16* __restrict__ fccp, const float* __restrict__ fccb,
                      float* __restrict__ cnet) {
  extern __shared__ _Float16 smem[];          // 16 KB
  _Float16* Ahi = smem;                       // 4096 f16
  _Float16* Alo = smem + 4096;
  const int tid = threadIdx.x, lane = tid & 63, wave = tid >> 6;
  const int p0 = blockIdx.x << 5;
  #pragma unroll
  for (int i = 0; i < 2; ++i) {
    int sidx = tid + (i << 8);                // 512 slots
    int m = sidx >> 4, kslot = sidx & 15, k0 = kslot << 3;
    float4 a = *(const float4*)&net[(size_t)(p0 + m) * 128 + k0];
    float4 c = *(const float4*)&net[(size_t)(p0 + m) * 128 + k0 + 4];
    float v[8] = {fmaxf(a.x, 0.f), fmaxf(a.y, 0.f), fmaxf(a.z, 0.f), fmaxf(a.w, 0.f),
                  fmaxf(c.x, 0.f), fmaxf(c.y, 0.f), fmaxf(c.z, 0.f), fmaxf(c.w, 0.f)};
    half8 hi, lo; splith8(v, hi, lo);
    int mt = m >> 4, mm = m & 15, s = kslot >> 2, quad = kslot & 3;
    int ln = mm + (quad << 4), kg = (mt << 2) + s;  // [0,8)
    int u = (kg << 6) + (ln ^ (kg & 7));
    *(half8*)&Ahi[u << 3] = hi;
    *(half8*)&Alo[u << 3] = lo;
  }
  __syncthreads();

  f32x4 am[2][2], ac[2][2];
  {
    int col = lane & 15;
    #pragma unroll
    for (int nt = 0; nt < 2; ++nt) {
      float bv = fccb[(wave << 5) + (nt << 4) + col];
      #pragma unroll
      for (int mt = 0; mt < 2; ++mt) {
        am[mt][nt] = (f32x4){bv, bv, bv, bv};
        ac[mt][nt] = (f32x4){0.f, 0.f, 0.f, 0.f};
      }
    }
  }
  const _Float16* flo = fccp + 16384;
  half8 ch[2], cl[2];
  #pragma unroll
  for (int nt = 0; nt < 2; ++nt) {
    int t = (wave << 1) + nt;
    size_t fo = (((size_t)(t << 2) << 6) + lane) << 3;
    ch[nt] = *(const half8*)&fccp[fo];
    cl[nt] = *(const half8*)&flo[fo];
  }
  for (int ks = 0; ks < 4; ++ks) {
    half8 nh[2], nl[2];
    int ksn = (ks + 1) & 3;
    #pragma unroll
    for (int nt = 0; nt < 2; ++nt) {
      int t = (wave << 1) + nt;
      size_t fo = (((size_t)((t << 2) + ksn) << 6) + lane) << 3;
      nh[nt] = *(const half8*)&fccp[fo];
      nl[nt] = *(const half8*)&flo[fo];
    }
    #pragma unroll
    for (int mt = 0; mt < 2; ++mt) {
      int kg = (mt << 2) + ks;
      int u = (kg << 6) + (lane ^ (kg & 7));
      half8 ah = *(const half8*)&Ahi[u << 3];
      half8 al = *(const half8*)&Alo[u << 3];
      #pragma unroll
      for (int nt = 0; nt < 2; ++nt) {
        am[mt][nt] = __builtin_amdgcn_mfma_f32_16x16x32_f16(ah, ch[nt], am[mt][nt], 0, 0, 0);
        ac[mt][nt] = __builtin_amdgcn_mfma_f32_16x16x32_f16(al, ch[nt], ac[mt][nt], 0, 0, 0);
        ac[mt][nt] = __builtin_amdgcn_mfma_f32_16x16x32_f16(ah, cl[nt], ac[mt][nt], 0, 0, 0);
      }
    }
    #pragma unroll
    for (int nt = 0; nt < 2; ++nt) { ch[nt] = nh[nt]; cl[nt] = nl[nt]; }
  }
  {
    int col = lane & 15, q = lane >> 4;
    #pragma unroll
    for (int mt = 0; mt < 2; ++mt) {
      #pragma unroll
      for (int r = 0; r < 4; ++r) {
        int m_g = p0 + (mt << 4) + (q << 2) + r;
        #pragma unroll
        for (int nt = 0; nt < 2; ++nt) {
          int n = (wave << 5) + (nt << 4) + col;
          cnet[(size_t)m_g * 128 + n] = fmaf(ac[mt][nt][r], INV4096, am[mt][nt][r]);
        }
      }
    }
  }
}

// ---------- divide by counts + transpose (B,R2,C) -> (B,C,R2) ----------
__launch_bounds__(256)
__global__ void k_finalize(const float* __restrict__ sums, const int* __restrict__ cnti,
                           float* __restrict__ out) {
  __shared__ float t[64 * 65];
  __shared__ float rc[64];
  const int bid = blockIdx.x;                 // 4 * 256 * 2 = 2048
  const int ct = bid & 1, rt = (bid >> 1) & 255, b = bid >> 9;
  const int r0 = rt << 6, c0 = ct << 6;
  const int tid = threadIdx.x, l16 = tid & 15, sl = tid >> 4;
  for (int rr = sl; rr < 64; rr += 16) {
    float4 v = *(const float4*)&sums[(size_t)((b << 14) + r0 + rr) * 128 + c0 + (l16 << 2)];
    int cb = l16 << 2;
    t[rr * 65 + cb + 0] = v.x; t[rr * 65 + cb + 1] = v.y;
    t[rr * 65 + cb + 2] = v.z; t[rr * 65 + cb + 3] = v.w;
  }
  if (tid < 64) rc[tid] = 1.f / fmaxf((float)cnti[(b << 14) + r0 + tid], 1.f);
  __syncthreads();
  for (int cc = sl; cc < 64; cc += 16) {
    int c = c0 + cc;
    int rb = l16 << 2;
    float4 o = make_float4(t[(rb + 0) * 65 + cc] * rc[rb + 0],
                           t[(rb + 1) * 65 + cc] * rc[rb + 1],
                           t[(rb + 2) * 65 + cc] * rc[rb + 2],
                           t[(rb + 3) * 65 + cc] * rc[rb + 3]);
    *(float4*)&out[(size_t)((b << 7) + c) * 16384 + r0 + rb] = o;
  }
}

// ---------- host launch ----------
extern "C" void kernel_launch(void* const* d_in, const int* in_sizes, int n_in,
                              void* d_out, int out_size, void* d_ws, size_t ws_size,
                              hipStream_t stream) {
  const float* points = (const float*)d_in[0];
  const float* posw   = (const float*)d_in[1];
  const float* posb   = (const float*)d_in[2];
  const float* fc0w   = (const float*)d_in[3];
  const float* fc0b   = (const float*)d_in[4];
  const float* fc1w   = (const float*)d_in[5];
  const float* fc1b   = (const float*)d_in[6];
  const float* scw    = (const float*)d_in[7];
  const float* fccw   = (const float*)d_in[8];
  const float* fccb   = (const float*)d_in[9];
  float* outp = (float*)d_out;

  // workspace: net 32MB | bins 32MB | sort arrays | packed weights  (~70 MB)
  float* net  = (float*)d_ws;
  float* bins = net + (size_t)BN * 128;        // also reused as cnet (fcc out)
  int* idxp   = (int*)(bins + (size_t)BN * 128);
  int* perm   = idxp + BN;
  int* sbin   = perm + BN;
  int* cnti   = sbin + BN;
  int* off    = cnti + BN;
  int* cursor = off + BN;
  _Float16* wp = (_Float16*)(cursor + BN);

  const _Float16* w0_ = wp;            // 5 x 65536 (hi|lo)
  const _Float16* ws_ = wp + 327680;   // 5 x 65536
  const _Float16* w1_ = wp + 655360;   // 5 x 32768
  const _Float16* fcc_ = wp + 819200;  // 32768

  k_zero4<<<64, 256, 0, stream>>>((float4*)cnti, 16384);
  k_idx<<<256, 256, 0, stream>>>(points, idxp, cnti);
  k_scan<<<4, 256, 0, stream>>>(cnti, off, cursor);
  k_scatter<<<256, 256, 0, stream>>>(idxp, cursor, perm, sbin);
  k_pack<<<208, 256, 0, stream>>>(fc0w, scw, fc1w, fccw, wp);

  k_rb<0><<<2048, 256, 32768, stream>>>(points, nullptr, perm, sbin, posw, posb,
                                        w0_, fc0b, w1_, fc1b, ws_, net);
  for (int l = 1; l < 5; ++l) {
    k_seg<<<16384, 256, 0, stream>>>(net, off, cnti, bins);
    k_rb<1><<<2048, 256, 32768, stream>>>(points, bins, perm, sbin, posw, posb,
                                          w0_ + (size_t)l * 65536, fc0b + l * 128,
                                          w1_ + (size_t)l * 32768, fc1b + l * 128,
                                          ws_ + (size_t)l * 65536, net);
  }
  // bins buffer reused as cnet (per-point features), then net reused as sums
  float* cnet = bins;
  float* sums = net;
  k_fcc<<<2048, 256, 16384, stream>>>(net, fcc_, fccb, cnet);
  k_segsum<<<16384, 256, 0, stream>>>(cnet, off, cnti, sums);
  k_finalize<<<2048, 256, 0, stream>>>(sums, cnti, outp);
}